// Round 8
// baseline (276.838 us; speedup 1.0000x reference)
//
#include <hip/hip_runtime.h>
#include <hip/hip_bf16.h>
#include <hip/hip_fp16.h>

#define GG 8
#define AA 65
#define BB 256

typedef __attribute__((ext_vector_type(8))) short bf16x8;
typedef __attribute__((ext_vector_type(4))) short s16x4;
typedef __attribute__((ext_vector_type(4))) float f32x4;
typedef _Float16 hf2 __attribute__((ext_vector_type(2)));
#define MFMA16(a, b, c) __builtin_amdgcn_mfma_f32_16x16x32_bf16(a, b, c, 0, 0, 0)

__device__ __forceinline__ void rz_taps(int o, float scale, int in_size,
                                        int& ia, int& ib, float& f) {
  float pos = (o + 0.5f) * scale - 0.5f;
  float fl = floorf(pos);
  int i0 = (int)fl;
  f = pos - fl;
  ia = i0 < 0 ? 0 : i0;
  int i1 = i0 + 1;
  ib = i1 > (in_size - 1) ? (in_size - 1) : i1;
}

// Compile-time 128->65 tap: pos = (j+0.5)*65/128-0.5 = (130j-63)/256 exactly.
#define JTAP(jc, ja, jb, fj) \
  const int num_ = 130 * (jc) - 63;               \
  const int fl_ = num_ >> 8;                      \
  const int ja = fl_ < 0 ? 0 : fl_;               \
  const int jb = (fl_ + 1 > 64) ? 64 : (fl_ + 1); \
  const float fj = (float)(num_ - (fl_ << 8)) * 0.00390625f;

__device__ __forceinline__ float gelu_exact(float v) {
  return 0.5f * v * (1.0f + erff(v * 0.70710678118654752f));
}

__device__ __forceinline__ short f2b(float f) {
  __hip_bfloat16 h = __float2bfloat16(f);
  return *reinterpret_cast<short*>(&h);
}
__device__ __forceinline__ float b2f(short s) {
  unsigned int u = ((unsigned int)(unsigned short)s) << 16;
  return __uint_as_float(u);
}

#define RSBN 0.99999500003749977f  // 1/sqrt(1+1e-5)

// ---------- PREP: weights->bf16, relAp/relATp, veA2 (all direct from inputs) ----------
__global__ void k_prep(const float* __restrict__ base, const float* __restrict__ wq,
                       const float* __restrict__ w1, const float* __restrict__ w2,
                       short* __restrict__ wqb, short* __restrict__ w1b,
                       short* __restrict__ w2b, float* __restrict__ relAp,
                       float* __restrict__ relATp, __half* __restrict__ veA2) {
  int blk = blockIdx.x;
  int tt = threadIdx.x;
  if (blk < 256) {             // weights
    int i = blk * 256 + tt;
    if (i < 32768) wqb[i] = f2b(wq[i]);
    w1b[i] = f2b(w1[i]);
    w2b[i] = f2b(w2[i]);
    return;
  }
  blk -= 256;
  if (blk < 265) {             // q_emb padded + k_emb transposed padded (65x65)
    int idx = blk * 256 + tt;
    if (idx >= 16 * AA * AA) return;
    int j = idx % AA;
    int r = idx / AA;
    int i = r % AA;
    int c = r / AA;
    int ia, ib, ja, jb; float fi, fj;
    rz_taps(i, 255.0f / 65.0f, 255, ia, ib, fi);
    rz_taps(j, 255.0f / 65.0f, 255, ja, jb, fj);
    const float* S = base + (size_t)c * 255 * 255;
    float v = (1.0f - fi) * ((1.0f - fj) * S[ia * 255 + ja] + fj * S[ia * 255 + jb])
            + fi * ((1.0f - fj) * S[ib * 255 + ja] + fj * S[ib * 255 + jb]);
    if (c < 8) relAp[c * 4420 + i * 68 + j] = v;
    else relATp[(c - 8) * 4420 + j * 68 + i] = v;
    return;
  }
  blk -= 265;
  {                            // veA2[c][i][72]: i-upsampled v_emb on 65-a grid, a-pair layout
    int idx = blk * 256 + tt;  // 16*128*72 = 147,456
    if (idx >= 16 * 128 * 72) return;
    int a = idx % 72;
    int r = idx / 72;
    int i = r & 127;
    int c = r >> 7;
    float v = 0.f;
    if (a < 65) {
      int ia, ib; float fi;
      rz_taps(i, 65.0f / 128.0f, 65, ia, ib, fi);
      int ja, jb; float fj;
      rz_taps(a, 255.0f / 65.0f, 255, ja, jb, fj);
      int p0a, p0b; float g0;
      rz_taps(ia, 255.0f / 65.0f, 255, p0a, p0b, g0);
      int p1a, p1b; float g1;
      rz_taps(ib, 255.0f / 65.0f, 255, p1a, p1b, g1);
      const float* S = base + (size_t)(16 + c) * 255 * 255;
      float r0 = (1.0f - g0) * ((1.0f - fj) * S[p0a * 255 + ja] + fj * S[p0a * 255 + jb])
               + g0 * ((1.0f - fj) * S[p0b * 255 + ja] + fj * S[p0b * 255 + jb]);
      float r1 = (1.0f - g1) * ((1.0f - fj) * S[p1a * 255 + ja] + fj * S[p1a * 255 + jb])
               + g1 * ((1.0f - fj) * S[p1b * 255 + ja] + fj * S[p1b * 255 + jb]);
      v = (1.0f - fi) * r0 + fi * r1;
    }
    veA2[idx] = __float2half(v);
  }
}

// ---------- XA: downsample x along i (128->65) -> xab[n][a][c][w] bf16 ----------
__global__ void k_xa(const float* __restrict__ x, short* __restrict__ xab) {
  int idx = blockIdx.x * 256 + threadIdx.x;  // 2,129,920
  if (idx >= 2 * 65 * 128 * 128) return;
  int w = idx & 127;
  int c = (idx >> 7) & 127;
  int r = idx >> 14;
  int a = r % 65, n = r / 65;
  int ia, ib; float f;
  rz_taps(a, 128.0f / 65.0f, 128, ia, ib, f);
  const float* src = x + ((size_t)(n * 128 + c) * 128) * 128 + w;
  float v = (1.0f - f) * src[(size_t)ia * 128] + f * src[(size_t)ib * 128];
  xab[idx] = f2b(v);
}

// ---------- MFMA GEMM 1: qkva[n][o][a][w] = bf16(BN(Wqkv . xa)) ----------
__global__ __launch_bounds__(256) void k_qkv_mfma(
    const short* __restrict__ xab, const short* __restrict__ wqb,
    const float* __restrict__ bg, const float* __restrict__ bb,
    short* __restrict__ out) {
  const int ob = blockIdx.x * 128;
  const int a = blockIdx.y;
  const int n = blockIdx.z;
  __shared__ short Asm[128 * 40];
  __shared__ short Bsm[128 * 40];
  const int t = threadIdx.x;
  const int lane = t & 63, wv = t >> 6;
  const int wm = wv >> 1, wn = wv & 1;
  const int lr = lane & 15, lk = (lane >> 4) * 8;
  f32x4 acc[4][4];
  #pragma unroll
  for (int i = 0; i < 4; ++i)
    #pragma unroll
    for (int j = 0; j < 4; ++j)
      #pragma unroll
      for (int q = 0; q < 4; ++q) acc[i][j][q] = 0.f;
  const short* X = xab + (size_t)(n * 65 + a) * 128 * 128;
  for (int k0 = 0; k0 < 128; k0 += 32) {
    #pragma unroll
    for (int i2 = 0; i2 < 2; ++i2) {
      int u = t + 256 * i2;
      int row = u >> 2, kq = (u & 3) * 8;
      *(bf16x8*)&Asm[row * 40 + kq] = *(const bf16x8*)&wqb[(ob + row) * 128 + k0 + kq];
    }
    #pragma unroll
    for (int i2 = 0; i2 < 2; ++i2) {
      int u = t + 256 * i2;
      int k = u >> 4, p8 = (u & 15) * 8;
      bf16x8 hv = *(const bf16x8*)&X[(k0 + k) * 128 + p8];
      #pragma unroll
      for (int j = 0; j < 8; ++j) Bsm[(p8 + j) * 40 + k] = hv[j];
    }
    __syncthreads();
    bf16x8 af[4], bfr[4];
    #pragma unroll
    for (int mf = 0; mf < 4; ++mf) af[mf] = *(bf16x8*)&Asm[(wm * 64 + mf * 16 + lr) * 40 + lk];
    #pragma unroll
    for (int nf = 0; nf < 4; ++nf) bfr[nf] = *(bf16x8*)&Bsm[(wn * 64 + nf * 16 + lr) * 40 + lk];
    #pragma unroll
    for (int mf = 0; mf < 4; ++mf)
      #pragma unroll
      for (int nf = 0; nf < 4; ++nf)
        acc[mf][nf] = MFMA16(af[mf], bfr[nf], acc[mf][nf]);
    __syncthreads();
  }
  #pragma unroll
  for (int mf = 0; mf < 4; ++mf) {
    #pragma unroll
    for (int r = 0; r < 4; ++r) {
      int o = ob + wm * 64 + mf * 16 + (lane >> 4) * 4 + r;
      float sc = bg[o] * RSBN, sh = bb[o];
      #pragma unroll
      for (int nf = 0; nf < 4; ++nf) {
        int p = wn * 64 + nf * 16 + lr;
        out[((size_t)(n * 256 + o) * 65 + a) * 128 + p] = f2b(acc[mf][nf][r] * sc + sh);
      }
    }
  }
}

// ---------- F: fused sim + softmax + dot2 sv/sve + bn_out (Ss/Pw LDS union) ----------
__global__ void k_attn(const short* __restrict__ qkva, const float* __restrict__ relAp,
                       const float* __restrict__ relATp, const __half* __restrict__ veA2,
                       const float* __restrict__ sg, const float* __restrict__ sb,
                       const float* __restrict__ og, const float* __restrict__ ob,
                       float* __restrict__ y) {
  int orig = blockIdx.x;
  int bg = ((orig & 7) << 8) + (orig >> 3);  // bijective XCD-chunk swizzle
  int b = bg >> 3, g = bg & 7;
  int n = b >> 7, w = b & 127;
  __shared__ float Ss[65 * 68];          // 17,680 B; reused as PwsH (16,896 B) after sync
  __shared__ float u0[1088];             // qs(520)|ksp(544); vasH (16*66 halves) after
  __shared__ float Pinvs[128];
  __half* PwsH = (__half*)Ss;
  float* qs = u0;
  float* ksp = u0 + 520;
  __half* vasH = (__half*)u0;
  int t = threadIdx.x;
  const short* Qbase = qkva + ((size_t)(n * 256 + g * 32) * 65) * 128 + w;

  // phase 1: stage q (ch 0..7) and k (ch 8..15) from qkva
  for (int l = t; l < 1040; l += 256) {
    int cc = l / 65, a = l - cc * 65;
    float v = b2f(Qbase[(size_t)l * 128]);
    if (cc < 8) qs[cc * 65 + a] = v;
    else ksp[(cc - 8) * 68 + a] = v;
  }
  __syncthreads();

  // phase 2: sim 65x65 (BN-combined qk+qr+kr), j-quad vectorized
  {
    float sqk = sg[g] * RSBN, sqr = sg[8 + g] * RSBN, skr = sg[16 + g] * RSBN;
    float badd = sb[g] + sb[8 + g] + sb[16 + g];
    for (int u = t; u < 65 * 17; u += 256) {
      int i = u / 17, jq = u - i * 17;
      float qv[8];
      #pragma unroll
      for (int c = 0; c < 8; ++c) qv[c] = qs[c * 65 + i];
      if (jq < 16) {
        int j0 = jq * 4;
        int lofs = i * 68 + j0;
        float qk0 = 0, qk1 = 0, qk2 = 0, qk3 = 0;
        float qr0 = 0, qr1 = 0, qr2 = 0, qr3 = 0;
        float kr0 = 0, kr1 = 0, kr2 = 0, kr3 = 0;
        #pragma unroll
        for (int c = 0; c < 8; ++c) {
          float4 kv = *(const float4*)&ksp[c * 68 + j0];
          float4 ra = *(const float4*)&relAp[c * 4420 + lofs];
          float4 rt = *(const float4*)&relATp[c * 4420 + lofs];
          float q = qv[c];
          qk0 += q * kv.x; qk1 += q * kv.y; qk2 += q * kv.z; qk3 += q * kv.w;
          qr0 += q * ra.x; qr1 += q * ra.y; qr2 += q * ra.z; qr3 += q * ra.w;
          kr0 += kv.x * rt.x; kr1 += kv.y * rt.y; kr2 += kv.z * rt.z; kr3 += kv.w * rt.w;
        }
        float4 res;
        res.x = sqk * qk0 + sqr * qr0 + skr * kr0 + badd;
        res.y = sqk * qk1 + sqr * qr1 + skr * kr1 + badd;
        res.z = sqk * qk2 + sqr * qr2 + skr * kr2 + badd;
        res.w = sqk * qk3 + sqr * qr3 + skr * kr3 + badd;
        *(float4*)&Ss[lofs] = res;
      } else {
        float qk = 0, qr = 0, kr = 0;
        int lofs = i * 68 + 64;
        #pragma unroll
        for (int c = 0; c < 8; ++c) {
          float kv = ksp[c * 68 + 64];
          qk += qv[c] * kv;
          qr += qv[c] * relAp[c * 4420 + lofs];
          kr += kv * relATp[c * 4420 + lofs];
        }
        Ss[lofs] = sqk * qk + sqr * qr + skr * kr + badd;
      }
    }
  }
  __syncthreads();

  // phase 3: v stage (overlays u0) + register-T softmax fold (Pw overwrites Ss after sync)
  for (int l = t; l < 16 * 66; l += 256) {
    int c = l / 66, a = l - c * 66;
    float v = (a < 65) ? b2f(Qbase[(size_t)((16 + c) * 65 + a) * 128]) : 0.f;
    vasH[l] = __float2half(v);
  }
  {
    const int i = t >> 1, h = t & 1;
    int ia, ib; float fi;
    rz_taps(i, 65.0f / 128.0f, 65, ia, ib, fi);
    const float* r0 = Ss + ia * 68 + h * 32;
    const float* r1 = Ss + ib * 68 + h * 32;
    const float wi0 = 1.0f - fi;
    float T[33];
    #pragma unroll
    for (int k = 0; k < 33; ++k) T[k] = wi0 * r0[k] + fi * r1[k];
    float mx = T[0];
    #pragma unroll
    for (int k = 1; k < 33; ++k) mx = fmaxf(mx, T[k]);
    mx = fmaxf(mx, __shfl_xor(mx, 1));
    float p[33];
    #pragma unroll
    for (int k = 0; k < 33; ++k) p[k] = 0.f;
    float sum = 0.f;
    if (h == 0) {
      #pragma unroll
      for (int j = 0; j < 64; ++j) {
        JTAP(j, ja, jb, fj);
        float v = (1.0f - fj) * T[ja] + fj * T[jb];
        float e = __expf(v - mx);
        sum += e;
        p[ja] += e * (1.0f - fj);
        p[jb] += e * fj;
      }
    } else {
      #pragma unroll
      for (int j = 64; j < 128; ++j) {
        JTAP(j, ja, jb, fj);
        float v = (1.0f - fj) * T[ja - 32] + fj * T[jb - 32];
        float e = __expf(v - mx);
        sum += e;
        p[ja - 32] += e * (1.0f - fj);
        p[jb - 32] += e * fj;
      }
    }
    sum += __shfl_xor(sum, 1);
    float other = __shfl_xor(h ? p[0] : p[32], 1);
    __syncthreads();   // all Ss reads complete before Pw overwrites the same LDS
    __half* prow = &PwsH[i * 66];
    if (h == 0) {
      p[32] += other;
      #pragma unroll
      for (int k = 0; k < 33; ++k) prow[k] = __float2half(p[k]);
      Pinvs[i] = 1.0f / sum;
    } else {
      p[0] += other;
      #pragma unroll
      for (int k = 0; k < 33; ++k) prow[32 + k] = __float2half(p[k]);
      prow[65] = __float2half(0.f);
    }
  }
  __syncthreads();

  // phase 4: dot2 contraction over 33 a-pairs; 4 independent chains; veA2 contiguous
  {
    const int i = t & 127;
    const int cg = t >> 7;
    const float inv = Pinvs[i];
    hf2 pw[33];
    const hf2* prow2 = (const hf2*)&PwsH[i * 66];
    #pragma unroll
    for (int ap = 0; ap < 33; ++ap) pw[ap] = prow2[ap];
    #pragma unroll
    for (int l = 0; l < 8; ++l) {
      const int c = cg * 8 + l;
      const hf2* vr = (const hf2*)&vasH[c * 66];
      const hf2* vp = (const hf2*)veA2 + ((size_t)c * 128 + i) * 36;
      float sv0 = 0.f, sv1 = 0.f, se0 = 0.f, se1 = 0.f;
      #pragma unroll
      for (int ap = 0; ap < 32; ap += 2) {
        sv0 = __builtin_amdgcn_fdot2(vr[ap], pw[ap], sv0, false);
        sv1 = __builtin_amdgcn_fdot2(vr[ap + 1], pw[ap + 1], sv1, false);
        se0 = __builtin_amdgcn_fdot2(vp[ap], pw[ap], se0, false);
        se1 = __builtin_amdgcn_fdot2(vp[ap + 1], pw[ap + 1], se1, false);
      }
      sv0 = __builtin_amdgcn_fdot2(vr[32], pw[32], sv0, false);
      se0 = __builtin_amdgcn_fdot2(vp[32], pw[32], se0, false);
      float sv = sv0 + sv1, se = se0 + se1;
      int c2 = g * 16 + c;
      int o0 = 2 * c2;
      float val = og[o0] * RSBN * (sv * inv) + ob[o0]
                + og[o0 + 1] * RSBN * (se * inv) + ob[o0 + 1];
      y[(((size_t)n * 128 + c2) * 128 + i) * 128 + w] = val;
    }
  }
}

// ---------- G: unified shift + instance-norm + bf16 write ----------
__global__ __launch_bounds__(256) void k_xn(const float* __restrict__ y,
                                            const float* __restrict__ inw,
                                            const float* __restrict__ inb,
                                            short* __restrict__ xnb) {
  int nc = blockIdx.x;
  int n = nc >> 7, cx = nc & 127;
  int sc_ch = cx, dh = 0, dw = 0;
  if (cx < 10)      { sc_ch = cx;      dw = -2; }
  else if (cx < 20) { sc_ch = cx - 10; dw = 2; }
  else if (cx < 30) { sc_ch = cx - 20; dh = -2; }
  else if (cx < 40) { sc_ch = cx - 30; dh = 2; }
  __shared__ short Sb[16384];
  __shared__ float sm[8];
  const float* src = y + ((size_t)n * 128 + sc_ch) * 16384;
  int t = threadIdx.x;
  #pragma unroll
  for (int l = 0; l < 16; ++l) {
    int q = t + l * 256;
    float4 v = *(const float4*)&src[q * 4];
    s16x4 o;
    o.x = f2b(v.x); o.y = f2b(v.y); o.z = f2b(v.z); o.w = f2b(v.w);
    *(s16x4*)&Sb[q * 4] = o;
  }
  __syncthreads();
  float s = 0.f, q2 = 0.f;
  for (int l = 0; l < 64; ++l) {
    int idx = t + l * 256;
    int h = idx >> 7, w = idx & 127;
    int hs = h + dh, ws = w + dw;
    float v = (hs >= 0 && hs < 128 && ws >= 0 && ws < 128) ? b2f(Sb[hs * 128 + ws]) : 0.f;
    s += v; q2 += v * v;
  }
  #pragma unroll
  for (int o = 32; o; o >>= 1) { s += __shfl_down(s, o); q2 += __shfl_down(q2, o); }
  if ((t & 63) == 0) { sm[(t >> 6) * 2] = s; sm[(t >> 6) * 2 + 1] = q2; }
  __syncthreads();
  float S_ = sm[0] + sm[2] + sm[4] + sm[6];
  float Q_ = sm[1] + sm[3] + sm[5] + sm[7];
  float mean = S_ * (1.0f / 16384.0f);
  float var = Q_ * (1.0f / 16384.0f) - mean * mean;
  float scale = inw[cx] * rsqrtf(var + 1e-5f);
  float shift = inb[cx] - mean * scale;
  short* dst = xnb + (size_t)nc * 16384;
  for (int l = 0; l < 64; ++l) {
    int idx = t + l * 256;
    int h = idx >> 7, w = idx & 127;
    int hs = h + dh, ws = w + dw;
    float v = (hs >= 0 && hs < 128 && ws >= 0 && ws < 128) ? b2f(Sb[hs * 128 + ws]) : 0.f;
    dst[idx] = f2b(v * scale + shift);
  }
}

// ---------- MFMA GEMM 2: h1 = gelu(W1 . xn) ----------
__global__ __launch_bounds__(256) void k_mlp1_mfma(
    const short* __restrict__ xnb, const short* __restrict__ w1b,
    short* __restrict__ h1) {
  const int ob = blockIdx.x * 128;
  const int pb = blockIdx.y * 128;
  const int n = blockIdx.z;
  __shared__ short Asm[128 * 40];
  __shared__ short Bsm[128 * 40];
  const int t = threadIdx.x;
  const int lane = t & 63, wv = t >> 6;
  const int wm = wv >> 1, wn = wv & 1;
  const int lr = lane & 15, lk = (lane >> 4) * 8;
  f32x4 acc[4][4];
  #pragma unroll
  for (int i = 0; i < 4; ++i)
    #pragma unroll
    for (int j = 0; j < 4; ++j)
      #pragma unroll
      for (int q = 0; q < 4; ++q) acc[i][j][q] = 0.f;
  const short* X = xnb + (size_t)n * 128 * 16384;
  for (int k0 = 0; k0 < 128; k0 += 32) {
    #pragma unroll
    for (int i2 = 0; i2 < 2; ++i2) {
      int u = t + 256 * i2;
      int row = u >> 2, kq = (u & 3) * 8;
      *(bf16x8*)&Asm[row * 40 + kq] = *(const bf16x8*)&w1b[(ob + row) * 128 + k0 + kq];
    }
    #pragma unroll
    for (int i2 = 0; i2 < 2; ++i2) {
      int u = t + 256 * i2;
      int k = u >> 4, p8 = (u & 15) * 8;
      bf16x8 hv = *(const bf16x8*)&X[(size_t)(k0 + k) * 16384 + pb + p8];
      #pragma unroll
      for (int j = 0; j < 8; ++j) Bsm[(p8 + j) * 40 + k] = hv[j];
    }
    __syncthreads();
    bf16x8 af[4], bfr[4];
    #pragma unroll
    for (int mf = 0; mf < 4; ++mf) af[mf] = *(bf16x8*)&Asm[(wm * 64 + mf * 16 + lr) * 40 + lk];
    #pragma unroll
    for (int nf = 0; nf < 4; ++nf) bfr[nf] = *(bf16x8*)&Bsm[(wn * 64 + nf * 16 + lr) * 40 + lk];
    #pragma unroll
    for (int mf = 0; mf < 4; ++mf)
      #pragma unroll
      for (int nf = 0; nf < 4; ++nf)
        acc[mf][nf] = MFMA16(af[mf], bfr[nf], acc[mf][nf]);
    __syncthreads();
  }
  #pragma unroll
  for (int mf = 0; mf < 4; ++mf)
    #pragma unroll
    for (int r = 0; r < 4; ++r) {
      int o = ob + wm * 64 + mf * 16 + (lane >> 4) * 4 + r;
      #pragma unroll
      for (int nf = 0; nf < 4; ++nf) {
        int p = pb + wn * 64 + nf * 16 + lr;
        h1[((size_t)(n * 512 + o)) * 16384 + p] = f2b(gelu_exact(acc[mf][nf][r]));
      }
    }
}

// ---------- MFMA GEMM 3: out = W2 . h1 + identity(y) ----------
__global__ __launch_bounds__(256) void k_mlp2_mfma(
    const short* __restrict__ h1, const short* __restrict__ w2b,
    const float* __restrict__ y, float* __restrict__ out) {
  const int pb = blockIdx.x * 128;
  const int ob = blockIdx.y * 128;
  const int n = blockIdx.z;
  __shared__ short Asm[128 * 40];
  __shared__ short Bsm[128 * 40];
  const int t = threadIdx.x;
  const int lane = t & 63, wv = t >> 6;
  const int wm = wv >> 1, wn = wv & 1;
  const int lr = lane & 15, lk = (lane >> 4) * 8;
  f32x4 acc[4][4];
  #pragma unroll
  for (int i = 0; i < 4; ++i)
    #pragma unroll
    for (int j = 0; j < 4; ++j)
      #pragma unroll
      for (int q = 0; q < 4; ++q) acc[i][j][q] = 0.f;
  const short* H = h1 + (size_t)n * 512 * 16384;
  for (int k0 = 0; k0 < 512; k0 += 32) {
    #pragma unroll
    for (int i2 = 0; i2 < 2; ++i2) {
      int u = t + 256 * i2;
      int row = u >> 2, kq = (u & 3) * 8;
      *(bf16x8*)&Asm[row * 40 + kq] = *(const bf16x8*)&w2b[(ob + row) * 512 + k0 + kq];
    }
    #pragma unroll
    for (int i2 = 0; i2 < 2; ++i2) {
      int u = t + 256 * i2;
      int k = u >> 4, p8 = (u & 15) * 8;
      bf16x8 hv = *(const bf16x8*)&H[(size_t)(k0 + k) * 16384 + pb + p8];
      #pragma unroll
      for (int j = 0; j < 8; ++j) Bsm[(p8 + j) * 40 + k] = hv[j];
    }
    __syncthreads();
    bf16x8 af[4], bfr[4];
    #pragma unroll
    for (int mf = 0; mf < 4; ++mf) af[mf] = *(bf16x8*)&Asm[(wm * 64 + mf * 16 + lr) * 40 + lk];
    #pragma unroll
    for (int nf = 0; nf < 4; ++nf) bfr[nf] = *(bf16x8*)&Bsm[(wn * 64 + nf * 16 + lr) * 40 + lk];
    #pragma unroll
    for (int mf = 0; mf < 4; ++mf)
      #pragma unroll
      for (int nf = 0; nf < 4; ++nf)
        acc[mf][nf] = MFMA16(af[mf], bfr[nf], acc[mf][nf]);
    __syncthreads();
  }
  #pragma unroll
  for (int mf = 0; mf < 4; ++mf)
    #pragma unroll
    for (int r = 0; r < 4; ++r) {
      int o = ob + wm * 64 + mf * 16 + (lane >> 4) * 4 + r;
      #pragma unroll
      for (int nf = 0; nf < 4; ++nf) {
        int p = pb + wn * 64 + nf * 16 + lr;
        size_t base = ((size_t)(n * 128 + o)) * 16384 + p;
        out[base] = acc[mf][nf][r] + y[base];
      }
    }
}

extern "C" void kernel_launch(void* const* d_in, const int* in_sizes, int n_in,
                              void* d_out, int out_size, void* d_ws, size_t ws_size,
                              hipStream_t stream) {
  const float* x        = (const float*)d_in[0];
  const float* w_qkv    = (const float*)d_in[1];
  const float* bn_qkv_g = (const float*)d_in[2];
  const float* bn_qkv_b = (const float*)d_in[3];
  const float* bn_sim_g = (const float*)d_in[4];
  const float* bn_sim_b = (const float*)d_in[5];
  const float* bn_out_g = (const float*)d_in[6];
  const float* bn_out_b = (const float*)d_in[7];
  const float* in_w     = (const float*)d_in[8];
  const float* in_b     = (const float*)d_in[9];
  const float* mlp_w1   = (const float*)d_in[10];
  const float* mlp_w2   = (const float*)d_in[11];
  const float* base_rel = (const float*)d_in[12];
  float* Wp = (float*)d_ws;

  float* relAp  = Wp + 0;           // 35,456
  float* relATp = Wp + 35456;       // 35,456
  __half* veA2  = (__half*)(Wp + 70912);    // 147,456 halves (73,728 f)
  float* yb     = Wp + 144640;      // 4,194,304
  short* wqb    = (short*)(Wp + 4338944);   // 32,768 shorts
  short* w1b    = (short*)(Wp + 4355328);   // 65,536 shorts
  short* w2b    = (short*)(Wp + 4388096);   // 65,536 shorts
  short* xnb    = (short*)(Wp + 4420864);   // 4,194,304 shorts
  short* xab    = (short*)(Wp + 6518016);   // 2,129,920 shorts (dead after qkv)
  short* qkva   = (short*)(Wp + 7582976);   // 4,259,840 shorts (dead after attn)
  short* h1b    = (short*)(Wp + 6518016);   // 16,777,216 shorts (overlays xab+qkva)
  // peak: 14,906,624 floats = 59.6 MB

  k_prep<<<dim3(1097), dim3(256), 0, stream>>>(base_rel, w_qkv, mlp_w1, mlp_w2,
                                               wqb, w1b, w2b, relAp, relATp, veA2);
  k_xa<<<dim3(8320), dim3(256), 0, stream>>>(x, xab);
  k_qkv_mfma<<<dim3(2, 65, 2), dim3(256), 0, stream>>>(xab, wqb, bn_qkv_g, bn_qkv_b, qkva);
  k_attn<<<dim3(2048), dim3(256), 0, stream>>>(qkva, relAp, relATp, veA2,
                                               bn_sim_g, bn_sim_b, bn_out_g, bn_out_b, yb);
  k_xn<<<dim3(256), dim3(256), 0, stream>>>(yb, in_w, in_b, xnb);
  k_mlp1_mfma<<<dim3(4, 128, 2), dim3(256), 0, stream>>>(xnb, w1b, h1b);
  k_mlp2_mfma<<<dim3(128, 1, 2), dim3(256), 0, stream>>>(h1b, w2b, yb, (float*)d_out);
}

// Round 9
// 192.989 us; speedup vs baseline: 1.4345x; 1.4345x over previous
//
#include <hip/hip_runtime.h>
#include <hip/hip_bf16.h>
#include <hip/hip_fp16.h>

#define GG 8
#define AA 65
#define BB 256

typedef __attribute__((ext_vector_type(8))) short bf16x8;
typedef __attribute__((ext_vector_type(4))) short s16x4;
typedef __attribute__((ext_vector_type(4))) float f32x4;
typedef _Float16 hf2 __attribute__((ext_vector_type(2)));
#define MFMA16(a, b, c) __builtin_amdgcn_mfma_f32_16x16x32_bf16(a, b, c, 0, 0, 0)

__device__ __forceinline__ void rz_taps(int o, float scale, int in_size,
                                        int& ia, int& ib, float& f) {
  float pos = (o + 0.5f) * scale - 0.5f;
  float fl = floorf(pos);
  int i0 = (int)fl;
  f = pos - fl;
  ia = i0 < 0 ? 0 : i0;
  int i1 = i0 + 1;
  ib = i1 > (in_size - 1) ? (in_size - 1) : i1;
}

// Compile-time 128->65 tap: pos = (j+0.5)*65/128-0.5 = (130j-63)/256 exactly.
#define JTAP(jc, ja, jb, fj) \
  const int num_ = 130 * (jc) - 63;               \
  const int fl_ = num_ >> 8;                      \
  const int ja = fl_ < 0 ? 0 : fl_;               \
  const int jb = (fl_ + 1 > 64) ? 64 : (fl_ + 1); \
  const float fj = (float)(num_ - (fl_ << 8)) * 0.00390625f;

__device__ __forceinline__ float gelu_exact(float v) {
  return 0.5f * v * (1.0f + erff(v * 0.70710678118654752f));
}

__device__ __forceinline__ short f2b(float f) {
  __hip_bfloat16 h = __float2bfloat16(f);
  return *reinterpret_cast<short*>(&h);
}
__device__ __forceinline__ float b2f(short s) {
  unsigned int u = ((unsigned int)(unsigned short)s) << 16;
  return __uint_as_float(u);
}

#define RSBN 0.99999500003749977f  // 1/sqrt(1+1e-5)

// ---------- PREP: weights->bf16, relAp/relATp, veA (wave-coalesced layout) ----------
__global__ void k_prep(const float* __restrict__ base, const float* __restrict__ wq,
                       const float* __restrict__ w1, const float* __restrict__ w2,
                       short* __restrict__ wqb, short* __restrict__ w1b,
                       short* __restrict__ w2b, float* __restrict__ relAp,
                       float* __restrict__ relATp, __half* __restrict__ veA) {
  int blk = blockIdx.x;
  int tt = threadIdx.x;
  if (blk < 256) {             // weights
    int i = blk * 256 + tt;
    if (i < 32768) wqb[i] = f2b(wq[i]);
    w1b[i] = f2b(w1[i]);
    w2b[i] = f2b(w2[i]);
    return;
  }
  blk -= 256;
  if (blk < 265) {             // q_emb padded + k_emb transposed padded (65x65)
    int idx = blk * 256 + tt;
    if (idx >= 16 * AA * AA) return;
    int j = idx % AA;
    int r = idx / AA;
    int i = r % AA;
    int c = r / AA;
    int ia, ib, ja, jb; float fi, fj;
    rz_taps(i, 255.0f / 65.0f, 255, ia, ib, fi);
    rz_taps(j, 255.0f / 65.0f, 255, ja, jb, fj);
    const float* S = base + (size_t)c * 255 * 255;
    float v = (1.0f - fi) * ((1.0f - fj) * S[ia * 255 + ja] + fj * S[ia * 255 + jb])
            + fi * ((1.0f - fj) * S[ib * 255 + ja] + fj * S[ib * 255 + jb]);
    if (c < 8) relAp[c * 4420 + i * 68 + j] = v;
    else relATp[(c - 8) * 4420 + j * 68 + i] = v;
    return;
  }
  blk -= 265;
  {  // veA[c][ap][128i] half2 (wave-coalesced: i innermost): i-upsampled v_emb
    int idx = blk * 256 + tt;  // 16*66*128 = 135,168
    if (idx >= 16 * 66 * 128) return;
    int i = idx & 127;
    int r = idx >> 7;
    int a = r % 66, c = r / 66;
    float v = 0.f;
    if (a < 65) {
      int ia, ib; float fi;
      rz_taps(i, 65.0f / 128.0f, 65, ia, ib, fi);
      int ja, jb; float fj;
      rz_taps(a, 255.0f / 65.0f, 255, ja, jb, fj);
      int p0a, p0b; float g0;
      rz_taps(ia, 255.0f / 65.0f, 255, p0a, p0b, g0);
      int p1a, p1b; float g1;
      rz_taps(ib, 255.0f / 65.0f, 255, p1a, p1b, g1);
      const float* S = base + (size_t)(16 + c) * 255 * 255;
      float r0 = (1.0f - g0) * ((1.0f - fj) * S[p0a * 255 + ja] + fj * S[p0a * 255 + jb])
               + g0 * ((1.0f - fj) * S[p0b * 255 + ja] + fj * S[p0b * 255 + jb]);
      float r1 = (1.0f - g1) * ((1.0f - fj) * S[p1a * 255 + ja] + fj * S[p1a * 255 + jb])
               + g1 * ((1.0f - fj) * S[p1b * 255 + ja] + fj * S[p1b * 255 + jb]);
      v = (1.0f - fi) * r0 + fi * r1;
    }
    veA[((size_t)(c * 33 + (a >> 1)) * 128 + i) * 2 + (a & 1)] = __float2half(v);
  }
}

// ---------- XA: downsample x along i (128->65) -> xab[n][a][c][w] bf16 ----------
__global__ void k_xa(const float* __restrict__ x, short* __restrict__ xab) {
  int idx = blockIdx.x * 256 + threadIdx.x;  // 2,129,920
  if (idx >= 2 * 65 * 128 * 128) return;
  int w = idx & 127;
  int c = (idx >> 7) & 127;
  int r = idx >> 14;
  int a = r % 65, n = r / 65;
  int ia, ib; float f;
  rz_taps(a, 128.0f / 65.0f, 128, ia, ib, f);
  const float* src = x + ((size_t)(n * 128 + c) * 128) * 128 + w;
  float v = (1.0f - f) * src[(size_t)ia * 128] + f * src[(size_t)ib * 128];
  xab[idx] = f2b(v);
}

// ---------- MFMA GEMM 1: qkva[n][o][a][w] = bf16(BN(Wqkv . xa)) ----------
__global__ __launch_bounds__(256) void k_qkv_mfma(
    const short* __restrict__ xab, const short* __restrict__ wqb,
    const float* __restrict__ bg, const float* __restrict__ bb,
    short* __restrict__ out) {
  const int ob = blockIdx.x * 128;
  const int a = blockIdx.y;
  const int n = blockIdx.z;
  __shared__ short Asm[128 * 40];
  __shared__ short Bsm[128 * 40];
  const int t = threadIdx.x;
  const int lane = t & 63, wv = t >> 6;
  const int wm = wv >> 1, wn = wv & 1;
  const int lr = lane & 15, lk = (lane >> 4) * 8;
  f32x4 acc[4][4];
  #pragma unroll
  for (int i = 0; i < 4; ++i)
    #pragma unroll
    for (int j = 0; j < 4; ++j)
      #pragma unroll
      for (int q = 0; q < 4; ++q) acc[i][j][q] = 0.f;
  const short* X = xab + (size_t)(n * 65 + a) * 128 * 128;
  for (int k0 = 0; k0 < 128; k0 += 32) {
    #pragma unroll
    for (int i2 = 0; i2 < 2; ++i2) {
      int u = t + 256 * i2;
      int row = u >> 2, kq = (u & 3) * 8;
      *(bf16x8*)&Asm[row * 40 + kq] = *(const bf16x8*)&wqb[(ob + row) * 128 + k0 + kq];
    }
    #pragma unroll
    for (int i2 = 0; i2 < 2; ++i2) {
      int u = t + 256 * i2;
      int k = u >> 4, p8 = (u & 15) * 8;
      bf16x8 hv = *(const bf16x8*)&X[(k0 + k) * 128 + p8];
      #pragma unroll
      for (int j = 0; j < 8; ++j) Bsm[(p8 + j) * 40 + k] = hv[j];
    }
    __syncthreads();
    bf16x8 af[4], bfr[4];
    #pragma unroll
    for (int mf = 0; mf < 4; ++mf) af[mf] = *(bf16x8*)&Asm[(wm * 64 + mf * 16 + lr) * 40 + lk];
    #pragma unroll
    for (int nf = 0; nf < 4; ++nf) bfr[nf] = *(bf16x8*)&Bsm[(wn * 64 + nf * 16 + lr) * 40 + lk];
    #pragma unroll
    for (int mf = 0; mf < 4; ++mf)
      #pragma unroll
      for (int nf = 0; nf < 4; ++nf)
        acc[mf][nf] = MFMA16(af[mf], bfr[nf], acc[mf][nf]);
    __syncthreads();
  }
  #pragma unroll
  for (int mf = 0; mf < 4; ++mf) {
    #pragma unroll
    for (int r = 0; r < 4; ++r) {
      int o = ob + wm * 64 + mf * 16 + (lane >> 4) * 4 + r;
      float sc = bg[o] * RSBN, sh = bb[o];
      #pragma unroll
      for (int nf = 0; nf < 4; ++nf) {
        int p = wn * 64 + nf * 16 + lr;
        out[((size_t)(n * 256 + o) * 65 + a) * 128 + p] = f2b(acc[mf][nf][r] * sc + sh);
      }
    }
  }
}

// ---------- F: fused sim + softmax + dot2 sv/sve + bn_out (Ss/Pw LDS union) ----------
__global__ void k_attn(const short* __restrict__ qkva, const float* __restrict__ relAp,
                       const float* __restrict__ relATp, const __half* __restrict__ veA,
                       const float* __restrict__ sg, const float* __restrict__ sb,
                       const float* __restrict__ og, const float* __restrict__ ob,
                       float* __restrict__ y) {
  int orig = blockIdx.x;
  int bg = ((orig & 7) << 8) + (orig >> 3);  // bijective XCD-chunk swizzle
  int b = bg >> 3, g = bg & 7;
  int n = b >> 7, w = b & 127;
  __shared__ float Ss[65 * 68];          // 17,680 B; reused as PwsH after sync
  __shared__ float u0[1088];             // qs(520)|ksp(544); vasH (16*66 halves) after
  __shared__ float Pinvs[128];
  __half* PwsH = (__half*)Ss;
  float* qs = u0;
  float* ksp = u0 + 520;
  __half* vasH = (__half*)u0;
  int t = threadIdx.x;
  const short* Qbase = qkva + ((size_t)(n * 256 + g * 32) * 65) * 128 + w;

  // phase 1: stage q (ch 0..7) and k (ch 8..15) from qkva
  for (int l = t; l < 1040; l += 256) {
    int cc = l / 65, a = l - cc * 65;
    float v = b2f(Qbase[(size_t)l * 128]);
    if (cc < 8) qs[cc * 65 + a] = v;
    else ksp[(cc - 8) * 68 + a] = v;
  }
  __syncthreads();

  // phase 2: sim 65x65 (BN-combined qk+qr+kr), j-quad vectorized
  {
    float sqk = sg[g] * RSBN, sqr = sg[8 + g] * RSBN, skr = sg[16 + g] * RSBN;
    float badd = sb[g] + sb[8 + g] + sb[16 + g];
    for (int u = t; u < 65 * 17; u += 256) {
      int i = u / 17, jq = u - i * 17;
      float qv[8];
      #pragma unroll
      for (int c = 0; c < 8; ++c) qv[c] = qs[c * 65 + i];
      if (jq < 16) {
        int j0 = jq * 4;
        int lofs = i * 68 + j0;
        float qk0 = 0, qk1 = 0, qk2 = 0, qk3 = 0;
        float qr0 = 0, qr1 = 0, qr2 = 0, qr3 = 0;
        float kr0 = 0, kr1 = 0, kr2 = 0, kr3 = 0;
        #pragma unroll
        for (int c = 0; c < 8; ++c) {
          float4 kv = *(const float4*)&ksp[c * 68 + j0];
          float4 ra = *(const float4*)&relAp[c * 4420 + lofs];
          float4 rt = *(const float4*)&relATp[c * 4420 + lofs];
          float q = qv[c];
          qk0 += q * kv.x; qk1 += q * kv.y; qk2 += q * kv.z; qk3 += q * kv.w;
          qr0 += q * ra.x; qr1 += q * ra.y; qr2 += q * ra.z; qr3 += q * ra.w;
          kr0 += kv.x * rt.x; kr1 += kv.y * rt.y; kr2 += kv.z * rt.z; kr3 += kv.w * rt.w;
        }
        float4 res;
        res.x = sqk * qk0 + sqr * qr0 + skr * kr0 + badd;
        res.y = sqk * qk1 + sqr * qr1 + skr * kr1 + badd;
        res.z = sqk * qk2 + sqr * qr2 + skr * kr2 + badd;
        res.w = sqk * qk3 + sqr * qr3 + skr * kr3 + badd;
        *(float4*)&Ss[lofs] = res;
      } else {
        float qk = 0, qr = 0, kr = 0;
        int lofs = i * 68 + 64;
        #pragma unroll
        for (int c = 0; c < 8; ++c) {
          float kv = ksp[c * 68 + 64];
          qk += qv[c] * kv;
          qr += qv[c] * relAp[c * 4420 + lofs];
          kr += kv * relATp[c * 4420 + lofs];
        }
        Ss[lofs] = sqk * qk + sqr * qr + skr * kr + badd;
      }
    }
  }
  __syncthreads();

  // phase 3: v stage (overlays u0) + register-T softmax fold (Pw overwrites Ss after sync)
  for (int l = t; l < 16 * 66; l += 256) {
    int c = l / 66, a = l - c * 66;
    float v = (a < 65) ? b2f(Qbase[(size_t)((16 + c) * 65 + a) * 128]) : 0.f;
    vasH[l] = __float2half(v);
  }
  {
    const int i = t >> 1, h = t & 1;
    int ia, ib; float fi;
    rz_taps(i, 65.0f / 128.0f, 65, ia, ib, fi);
    const float* r0 = Ss + ia * 68 + h * 32;
    const float* r1 = Ss + ib * 68 + h * 32;
    const float wi0 = 1.0f - fi;
    float T[33];
    #pragma unroll
    for (int k = 0; k < 33; ++k) T[k] = wi0 * r0[k] + fi * r1[k];
    float mx = T[0];
    #pragma unroll
    for (int k = 1; k < 33; ++k) mx = fmaxf(mx, T[k]);
    mx = fmaxf(mx, __shfl_xor(mx, 1));
    float p[33];
    #pragma unroll
    for (int k = 0; k < 33; ++k) p[k] = 0.f;
    float sum = 0.f;
    if (h == 0) {
      #pragma unroll
      for (int j = 0; j < 64; ++j) {
        JTAP(j, ja, jb, fj);
        float v = (1.0f - fj) * T[ja] + fj * T[jb];
        float e = __expf(v - mx);
        sum += e;
        p[ja] += e * (1.0f - fj);
        p[jb] += e * fj;
      }
    } else {
      #pragma unroll
      for (int j = 64; j < 128; ++j) {
        JTAP(j, ja, jb, fj);
        float v = (1.0f - fj) * T[ja - 32] + fj * T[jb - 32];
        float e = __expf(v - mx);
        sum += e;
        p[ja - 32] += e * (1.0f - fj);
        p[jb - 32] += e * fj;
      }
    }
    sum += __shfl_xor(sum, 1);
    float other = __shfl_xor(h ? p[0] : p[32], 1);
    __syncthreads();   // all Ss reads complete before Pw overwrites the same LDS
    __half* prow = &PwsH[i * 66];
    if (h == 0) {
      p[32] += other;
      #pragma unroll
      for (int k = 0; k < 33; ++k) prow[k] = __float2half(p[k]);
      Pinvs[i] = 1.0f / sum;
    } else {
      p[0] += other;
      #pragma unroll
      for (int k = 0; k < 33; ++k) prow[32 + k] = __float2half(p[k]);
      prow[65] = __float2half(0.f);
    }
  }
  __syncthreads();

  // phase 4: dot2 contraction over 33 a-pairs; 2-chain ILP; wave-coalesced veA
  {
    const int i = t & 127;
    const int cg = t >> 7;
    const float inv = Pinvs[i];
    hf2 pw[33];
    const hf2* prow2 = (const hf2*)&PwsH[i * 66];
    #pragma unroll
    for (int ap = 0; ap < 33; ++ap) pw[ap] = prow2[ap];
    #pragma unroll
    for (int l = 0; l < 8; ++l) {
      const int c = cg * 8 + l;
      const hf2* vr = (const hf2*)&vasH[c * 66];
      const hf2* vp = (const hf2*)veA + (size_t)(c * 33) * 128 + i;
      float sv0 = 0.f, sv1 = 0.f, se0 = 0.f, se1 = 0.f;
      #pragma unroll
      for (int ap = 0; ap < 32; ap += 2) {
        sv0 = __builtin_amdgcn_fdot2(vr[ap], pw[ap], sv0, false);
        sv1 = __builtin_amdgcn_fdot2(vr[ap + 1], pw[ap + 1], sv1, false);
        se0 = __builtin_amdgcn_fdot2(vp[(size_t)ap * 128], pw[ap], se0, false);
        se1 = __builtin_amdgcn_fdot2(vp[(size_t)(ap + 1) * 128], pw[ap + 1], se1, false);
      }
      sv0 = __builtin_amdgcn_fdot2(vr[32], pw[32], sv0, false);
      se0 = __builtin_amdgcn_fdot2(vp[(size_t)32 * 128], pw[32], se0, false);
      float sv = sv0 + sv1, se = se0 + se1;
      int c2 = g * 16 + c;
      int o0 = 2 * c2;
      float val = og[o0] * RSBN * (sv * inv) + ob[o0]
                + og[o0 + 1] * RSBN * (se * inv) + ob[o0 + 1];
      y[(((size_t)n * 128 + c2) * 128 + i) * 128 + w] = val;
    }
  }
}

// ---------- G: unified shift + instance-norm + bf16 write ----------
__global__ __launch_bounds__(256) void k_xn(const float* __restrict__ y,
                                            const float* __restrict__ inw,
                                            const float* __restrict__ inb,
                                            short* __restrict__ xnb) {
  int nc = blockIdx.x;
  int n = nc >> 7, cx = nc & 127;
  int sc_ch = cx, dh = 0, dw = 0;
  if (cx < 10)      { sc_ch = cx;      dw = -2; }
  else if (cx < 20) { sc_ch = cx - 10; dw = 2; }
  else if (cx < 30) { sc_ch = cx - 20; dh = -2; }
  else if (cx < 40) { sc_ch = cx - 30; dh = 2; }
  __shared__ short Sb[16384];
  __shared__ float sm[8];
  const float* src = y + ((size_t)n * 128 + sc_ch) * 16384;
  int t = threadIdx.x;
  #pragma unroll
  for (int l = 0; l < 16; ++l) {
    int q = t + l * 256;
    float4 v = *(const float4*)&src[q * 4];
    s16x4 o;
    o.x = f2b(v.x); o.y = f2b(v.y); o.z = f2b(v.z); o.w = f2b(v.w);
    *(s16x4*)&Sb[q * 4] = o;
  }
  __syncthreads();
  float s = 0.f, q2 = 0.f;
  for (int l = 0; l < 64; ++l) {
    int idx = t + l * 256;
    int h = idx >> 7, w = idx & 127;
    int hs = h + dh, ws = w + dw;
    float v = (hs >= 0 && hs < 128 && ws >= 0 && ws < 128) ? b2f(Sb[hs * 128 + ws]) : 0.f;
    s += v; q2 += v * v;
  }
  #pragma unroll
  for (int o = 32; o; o >>= 1) { s += __shfl_down(s, o); q2 += __shfl_down(q2, o); }
  if ((t & 63) == 0) { sm[(t >> 6) * 2] = s; sm[(t >> 6) * 2 + 1] = q2; }
  __syncthreads();
  float S_ = sm[0] + sm[2] + sm[4] + sm[6];
  float Q_ = sm[1] + sm[3] + sm[5] + sm[7];
  float mean = S_ * (1.0f / 16384.0f);
  float var = Q_ * (1.0f / 16384.0f) - mean * mean;
  float scale = inw[cx] * rsqrtf(var + 1e-5f);
  float shift = inb[cx] - mean * scale;
  short* dst = xnb + (size_t)nc * 16384;
  for (int l = 0; l < 64; ++l) {
    int idx = t + l * 256;
    int h = idx >> 7, w = idx & 127;
    int hs = h + dh, ws = w + dw;
    float v = (hs >= 0 && hs < 128 && ws >= 0 && ws < 128) ? b2f(Sb[hs * 128 + ws]) : 0.f;
    dst[idx] = f2b(v * scale + shift);
  }
}

// ---------- MFMA GEMM 2: h1 = gelu(W1 . xn) ----------
__global__ __launch_bounds__(256) void k_mlp1_mfma(
    const short* __restrict__ xnb, const short* __restrict__ w1b,
    short* __restrict__ h1) {
  const int ob = blockIdx.x * 128;
  const int pb = blockIdx.y * 128;
  const int n = blockIdx.z;
  __shared__ short Asm[128 * 40];
  __shared__ short Bsm[128 * 40];
  const int t = threadIdx.x;
  const int lane = t & 63, wv = t >> 6;
  const int wm = wv >> 1, wn = wv & 1;
  const int lr = lane & 15, lk = (lane >> 4) * 8;
  f32x4 acc[4][4];
  #pragma unroll
  for (int i = 0; i < 4; ++i)
    #pragma unroll
    for (int j = 0; j < 4; ++j)
      #pragma unroll
      for (int q = 0; q < 4; ++q) acc[i][j][q] = 0.f;
  const short* X = xnb + (size_t)n * 128 * 16384;
  for (int k0 = 0; k0 < 128; k0 += 32) {
    #pragma unroll
    for (int i2 = 0; i2 < 2; ++i2) {
      int u = t + 256 * i2;
      int row = u >> 2, kq = (u & 3) * 8;
      *(bf16x8*)&Asm[row * 40 + kq] = *(const bf16x8*)&w1b[(ob + row) * 128 + k0 + kq];
    }
    #pragma unroll
    for (int i2 = 0; i2 < 2; ++i2) {
      int u = t + 256 * i2;
      int k = u >> 4, p8 = (u & 15) * 8;
      bf16x8 hv = *(const bf16x8*)&X[(size_t)(k0 + k) * 16384 + pb + p8];
      #pragma unroll
      for (int j = 0; j < 8; ++j) Bsm[(p8 + j) * 40 + k] = hv[j];
    }
    __syncthreads();
    bf16x8 af[4], bfr[4];
    #pragma unroll
    for (int mf = 0; mf < 4; ++mf) af[mf] = *(bf16x8*)&Asm[(wm * 64 + mf * 16 + lr) * 40 + lk];
    #pragma unroll
    for (int nf = 0; nf < 4; ++nf) bfr[nf] = *(bf16x8*)&Bsm[(wn * 64 + nf * 16 + lr) * 40 + lk];
    #pragma unroll
    for (int mf = 0; mf < 4; ++mf)
      #pragma unroll
      for (int nf = 0; nf < 4; ++nf)
        acc[mf][nf] = MFMA16(af[mf], bfr[nf], acc[mf][nf]);
    __syncthreads();
  }
  #pragma unroll
  for (int mf = 0; mf < 4; ++mf)
    #pragma unroll
    for (int r = 0; r < 4; ++r) {
      int o = ob + wm * 64 + mf * 16 + (lane >> 4) * 4 + r;
      #pragma unroll
      for (int nf = 0; nf < 4; ++nf) {
        int p = pb + wn * 64 + nf * 16 + lr;
        h1[((size_t)(n * 512 + o)) * 16384 + p] = f2b(gelu_exact(acc[mf][nf][r]));
      }
    }
}

// ---------- MFMA GEMM 3: out = W2 . h1 + identity(y) ----------
__global__ __launch_bounds__(256) void k_mlp2_mfma(
    const short* __restrict__ h1, const short* __restrict__ w2b,
    const float* __restrict__ y, float* __restrict__ out) {
  const int pb = blockIdx.x * 128;
  const int ob = blockIdx.y * 128;
  const int n = blockIdx.z;
  __shared__ short Asm[128 * 40];
  __shared__ short Bsm[128 * 40];
  const int t = threadIdx.x;
  const int lane = t & 63, wv = t >> 6;
  const int wm = wv >> 1, wn = wv & 1;
  const int lr = lane & 15, lk = (lane >> 4) * 8;
  f32x4 acc[4][4];
  #pragma unroll
  for (int i = 0; i < 4; ++i)
    #pragma unroll
    for (int j = 0; j < 4; ++j)
      #pragma unroll
      for (int q = 0; q < 4; ++q) acc[i][j][q] = 0.f;
  const short* H = h1 + (size_t)n * 512 * 16384;
  for (int k0 = 0; k0 < 512; k0 += 32) {
    #pragma unroll
    for (int i2 = 0; i2 < 2; ++i2) {
      int u = t + 256 * i2;
      int row = u >> 2, kq = (u & 3) * 8;
      *(bf16x8*)&Asm[row * 40 + kq] = *(const bf16x8*)&w2b[(ob + row) * 512 + k0 + kq];
    }
    #pragma unroll
    for (int i2 = 0; i2 < 2; ++i2) {
      int u = t + 256 * i2;
      int k = u >> 4, p8 = (u & 15) * 8;
      bf16x8 hv = *(const bf16x8*)&H[(size_t)(k0 + k) * 16384 + pb + p8];
      #pragma unroll
      for (int j = 0; j < 8; ++j) Bsm[(p8 + j) * 40 + k] = hv[j];
    }
    __syncthreads();
    bf16x8 af[4], bfr[4];
    #pragma unroll
    for (int mf = 0; mf < 4; ++mf) af[mf] = *(bf16x8*)&Asm[(wm * 64 + mf * 16 + lr) * 40 + lk];
    #pragma unroll
    for (int nf = 0; nf < 4; ++nf) bfr[nf] = *(bf16x8*)&Bsm[(wn * 64 + nf * 16 + lr) * 40 + lk];
    #pragma unroll
    for (int mf = 0; mf < 4; ++mf)
      #pragma unroll
      for (int nf = 0; nf < 4; ++nf)
        acc[mf][nf] = MFMA16(af[mf], bfr[nf], acc[mf][nf]);
    __syncthreads();
  }
  #pragma unroll
  for (int mf = 0; mf < 4; ++mf)
    #pragma unroll
    for (int r = 0; r < 4; ++r) {
      int o = ob + wm * 64 + mf * 16 + (lane >> 4) * 4 + r;
      #pragma unroll
      for (int nf = 0; nf < 4; ++nf) {
        int p = pb + wn * 64 + nf * 16 + lr;
        size_t base = ((size_t)(n * 128 + o)) * 16384 + p;
        out[base] = acc[mf][nf][r] + y[base];
      }
    }
}

extern "C" void kernel_launch(void* const* d_in, const int* in_sizes, int n_in,
                              void* d_out, int out_size, void* d_ws, size_t ws_size,
                              hipStream_t stream) {
  const float* x        = (const float*)d_in[0];
  const float* w_qkv    = (const float*)d_in[1];
  const float* bn_qkv_g = (const float*)d_in[2];
  const float* bn_qkv_b = (const float*)d_in[3];
  const float* bn_sim_g = (const float*)d_in[4];
  const float* bn_sim_b = (const float*)d_in[5];
  const float* bn_out_g = (const float*)d_in[6];
  const float* bn_out_b = (const float*)d_in[7];
  const float* in_w     = (const float*)d_in[8];
  const float* in_b     = (const float*)d_in[9];
  const float* mlp_w1   = (const float*)d_in[10];
  const float* mlp_w2   = (const float*)d_in[11];
  const float* base_rel = (const float*)d_in[12];
  float* Wp = (float*)d_ws;

  float* relAp  = Wp + 0;           // 35,456
  float* relATp = Wp + 35456;       // 35,456
  __half* veA   = (__half*)(Wp + 70912);    // 135,168 halves (67,584 f)
  float* yb     = Wp + 138496;      // 4,194,304
  short* wqb    = (short*)(Wp + 4332800);   // 32,768 shorts
  short* w1b    = (short*)(Wp + 4349184);   // 65,536 shorts
  short* w2b    = (short*)(Wp + 4381952);   // 65,536 shorts
  short* xnb    = (short*)(Wp + 4414720);   // 4,194,304 shorts
  short* xab    = (short*)(Wp + 6511872);   // 2,129,920 shorts (dead after qkv)
  short* qkva   = (short*)(Wp + 7576832);   // 4,259,840 shorts (dead after attn)
  short* h1b    = (short*)(Wp + 6511872);   // 16,777,216 shorts (overlays xab+qkva)
  // peak: 14,900,480 floats = 59.6 MB

  k_prep<<<dim3(1049), dim3(256), 0, stream>>>(base_rel, w_qkv, mlp_w1, mlp_w2,
                                               wqb, w1b, w2b, relAp, relATp, veA);
  k_xa<<<dim3(8320), dim3(256), 0, stream>>>(x, xab);
  k_qkv_mfma<<<dim3(2, 65, 2), dim3(256), 0, stream>>>(xab, wqb, bn_qkv_g, bn_qkv_b, qkva);
  k_attn<<<dim3(2048), dim3(256), 0, stream>>>(qkva, relAp, relATp, veA,
                                               bn_sim_g, bn_sim_b, bn_out_g, bn_out_b, yb);
  k_xn<<<dim3(256), dim3(256), 0, stream>>>(yb, in_w, in_b, xnb);
  k_mlp1_mfma<<<dim3(4, 128, 2), dim3(256), 0, stream>>>(xnb, w1b, h1b);
  k_mlp2_mfma<<<dim3(128, 1, 2), dim3(256), 0, stream>>>(h1b, w2b, yb, (float*)d_out);
}

// Round 10
// 180.801 us; speedup vs baseline: 1.5312x; 1.0674x over previous
//
#include <hip/hip_runtime.h>
#include <hip/hip_bf16.h>
#include <hip/hip_fp16.h>

#define GG 8
#define AA 65
#define BB 256

typedef __attribute__((ext_vector_type(8))) short bf16x8;
typedef __attribute__((ext_vector_type(4))) short s16x4;
typedef __attribute__((ext_vector_type(4))) float f32x4;
typedef _Float16 hf2 __attribute__((ext_vector_type(2)));
#define MFMA16(a, b, c) __builtin_amdgcn_mfma_f32_16x16x32_bf16(a, b, c, 0, 0, 0)

__device__ __forceinline__ void rz_taps(int o, float scale, int in_size,
                                        int& ia, int& ib, float& f) {
  float pos = (o + 0.5f) * scale - 0.5f;
  float fl = floorf(pos);
  int i0 = (int)fl;
  f = pos - fl;
  ia = i0 < 0 ? 0 : i0;
  int i1 = i0 + 1;
  ib = i1 > (in_size - 1) ? (in_size - 1) : i1;
}

// Compile-time 128->65 tap: pos = (j+0.5)*65/128-0.5 = (130j-63)/256 exactly.
#define JTAP(jc, ja, jb, fj) \
  const int num_ = 130 * (jc) - 63;               \
  const int fl_ = num_ >> 8;                      \
  const int ja = fl_ < 0 ? 0 : fl_;               \
  const int jb = (fl_ + 1 > 64) ? 64 : (fl_ + 1); \
  const float fj = (float)(num_ - (fl_ << 8)) * 0.00390625f;

__device__ __forceinline__ float gelu_exact(float v) {
  return 0.5f * v * (1.0f + erff(v * 0.70710678118654752f));
}

__device__ __forceinline__ short f2b(float f) {
  __hip_bfloat16 h = __float2bfloat16(f);
  return *reinterpret_cast<short*>(&h);
}
__device__ __forceinline__ float b2f(short s) {
  unsigned int u = ((unsigned int)(unsigned short)s) << 16;
  return __uint_as_float(u);
}

#define RSBN 0.99999500003749977f  // 1/sqrt(1+1e-5)

// ---------- PREP: weights->bf16, relAp/relATp, veA (wave-coalesced layout) ----------
__global__ void k_prep(const float* __restrict__ base, const float* __restrict__ wq,
                       const float* __restrict__ w1, const float* __restrict__ w2,
                       short* __restrict__ wqb, short* __restrict__ w1b,
                       short* __restrict__ w2b, float* __restrict__ relAp,
                       float* __restrict__ relATp, __half* __restrict__ veA) {
  int blk = blockIdx.x;
  int tt = threadIdx.x;
  if (blk < 256) {             // weights
    int i = blk * 256 + tt;
    if (i < 32768) wqb[i] = f2b(wq[i]);
    w1b[i] = f2b(w1[i]);
    w2b[i] = f2b(w2[i]);
    return;
  }
  blk -= 256;
  if (blk < 265) {             // q_emb padded + k_emb transposed padded (65x65)
    int idx = blk * 256 + tt;
    if (idx >= 16 * AA * AA) return;
    int j = idx % AA;
    int r = idx / AA;
    int i = r % AA;
    int c = r / AA;
    int ia, ib, ja, jb; float fi, fj;
    rz_taps(i, 255.0f / 65.0f, 255, ia, ib, fi);
    rz_taps(j, 255.0f / 65.0f, 255, ja, jb, fj);
    const float* S = base + (size_t)c * 255 * 255;
    float v = (1.0f - fi) * ((1.0f - fj) * S[ia * 255 + ja] + fj * S[ia * 255 + jb])
            + fi * ((1.0f - fj) * S[ib * 255 + ja] + fj * S[ib * 255 + jb]);
    if (c < 8) relAp[c * 4420 + i * 68 + j] = v;
    else relATp[(c - 8) * 4420 + j * 68 + i] = v;
    return;
  }
  blk -= 265;
  {  // veA[c][ap][128i] half2 (wave-coalesced: i innermost): i-upsampled v_emb
    int idx = blk * 256 + tt;  // 16*66*128 = 135,168
    if (idx >= 16 * 66 * 128) return;
    int i = idx & 127;
    int r = idx >> 7;
    int a = r % 66, c = r / 66;
    float v = 0.f;
    if (a < 65) {
      int ia, ib; float fi;
      rz_taps(i, 65.0f / 128.0f, 65, ia, ib, fi);
      int ja, jb; float fj;
      rz_taps(a, 255.0f / 65.0f, 255, ja, jb, fj);
      int p0a, p0b; float g0;
      rz_taps(ia, 255.0f / 65.0f, 255, p0a, p0b, g0);
      int p1a, p1b; float g1;
      rz_taps(ib, 255.0f / 65.0f, 255, p1a, p1b, g1);
      const float* S = base + (size_t)(16 + c) * 255 * 255;
      float r0 = (1.0f - g0) * ((1.0f - fj) * S[p0a * 255 + ja] + fj * S[p0a * 255 + jb])
               + g0 * ((1.0f - fj) * S[p0b * 255 + ja] + fj * S[p0b * 255 + jb]);
      float r1 = (1.0f - g1) * ((1.0f - fj) * S[p1a * 255 + ja] + fj * S[p1a * 255 + jb])
               + g1 * ((1.0f - fj) * S[p1b * 255 + ja] + fj * S[p1b * 255 + jb]);
      v = (1.0f - fi) * r0 + fi * r1;
    }
    veA[((size_t)(c * 33 + (a >> 1)) * 128 + i) * 2 + (a & 1)] = __float2half(v);
  }
}

// ---------- XA: downsample x along i (128->65) -> xab[n][a][c][w] bf16 ----------
__global__ void k_xa(const float* __restrict__ x, short* __restrict__ xab) {
  int idx = blockIdx.x * 256 + threadIdx.x;  // 2,129,920
  if (idx >= 2 * 65 * 128 * 128) return;
  int w = idx & 127;
  int c = (idx >> 7) & 127;
  int r = idx >> 14;
  int a = r % 65, n = r / 65;
  int ia, ib; float f;
  rz_taps(a, 128.0f / 65.0f, 128, ia, ib, f);
  const float* src = x + ((size_t)(n * 128 + c) * 128) * 128 + w;
  float v = (1.0f - f) * src[(size_t)ia * 128] + f * src[(size_t)ib * 128];
  xab[idx] = f2b(v);
}

// ---------- MFMA GEMM 1: qkva[n][o][a][w] = bf16(BN(Wqkv . xa)) ----------
__global__ __launch_bounds__(256) void k_qkv_mfma(
    const short* __restrict__ xab, const short* __restrict__ wqb,
    const float* __restrict__ bg, const float* __restrict__ bb,
    short* __restrict__ out) {
  const int ob = blockIdx.x * 128;
  const int a = blockIdx.y;
  const int n = blockIdx.z;
  __shared__ short Asm[128 * 40];
  __shared__ short Bsm[128 * 40];
  const int t = threadIdx.x;
  const int lane = t & 63, wv = t >> 6;
  const int wm = wv >> 1, wn = wv & 1;
  const int lr = lane & 15, lk = (lane >> 4) * 8;
  f32x4 acc[4][4];
  #pragma unroll
  for (int i = 0; i < 4; ++i)
    #pragma unroll
    for (int j = 0; j < 4; ++j)
      #pragma unroll
      for (int q = 0; q < 4; ++q) acc[i][j][q] = 0.f;
  const short* X = xab + (size_t)(n * 65 + a) * 128 * 128;
  for (int k0 = 0; k0 < 128; k0 += 32) {
    #pragma unroll
    for (int i2 = 0; i2 < 2; ++i2) {
      int u = t + 256 * i2;
      int row = u >> 2, kq = (u & 3) * 8;
      *(bf16x8*)&Asm[row * 40 + kq] = *(const bf16x8*)&wqb[(ob + row) * 128 + k0 + kq];
    }
    #pragma unroll
    for (int i2 = 0; i2 < 2; ++i2) {
      int u = t + 256 * i2;
      int k = u >> 4, p8 = (u & 15) * 8;
      bf16x8 hv = *(const bf16x8*)&X[(k0 + k) * 128 + p8];
      #pragma unroll
      for (int j = 0; j < 8; ++j) Bsm[(p8 + j) * 40 + k] = hv[j];
    }
    __syncthreads();
    bf16x8 af[4], bfr[4];
    #pragma unroll
    for (int mf = 0; mf < 4; ++mf) af[mf] = *(bf16x8*)&Asm[(wm * 64 + mf * 16 + lr) * 40 + lk];
    #pragma unroll
    for (int nf = 0; nf < 4; ++nf) bfr[nf] = *(bf16x8*)&Bsm[(wn * 64 + nf * 16 + lr) * 40 + lk];
    #pragma unroll
    for (int mf = 0; mf < 4; ++mf)
      #pragma unroll
      for (int nf = 0; nf < 4; ++nf)
        acc[mf][nf] = MFMA16(af[mf], bfr[nf], acc[mf][nf]);
    __syncthreads();
  }
  #pragma unroll
  for (int mf = 0; mf < 4; ++mf) {
    #pragma unroll
    for (int r = 0; r < 4; ++r) {
      int o = ob + wm * 64 + mf * 16 + (lane >> 4) * 4 + r;
      float sc = bg[o] * RSBN, sh = bb[o];
      #pragma unroll
      for (int nf = 0; nf < 4; ++nf) {
        int p = wn * 64 + nf * 16 + lr;
        out[((size_t)(n * 256 + o) * 65 + a) * 128 + p] = f2b(acc[mf][nf][r] * sc + sh);
      }
    }
  }
}

// ---------- F: fused sim + softmax + dot2 sv/sve + bn_out; writes yT coalesced ----------
__global__ void k_attn(const short* __restrict__ qkva, const float* __restrict__ relAp,
                       const float* __restrict__ relATp, const __half* __restrict__ veA,
                       const float* __restrict__ sg, const float* __restrict__ sb,
                       const float* __restrict__ og, const float* __restrict__ ob,
                       float* __restrict__ yT) {
  int orig = blockIdx.x;
  int bg = ((orig & 7) << 8) + (orig >> 3);  // bijective XCD-chunk swizzle
  int b = bg >> 3, g = bg & 7;
  int n = b >> 7, w = b & 127;
  __shared__ float Ss[65 * 68];          // 17,680 B; reused as PwsH after sync
  __shared__ float u0[1088];             // qs(520)|ksp(544); vasH (16*66 halves) after
  __shared__ float Pinvs[128];
  __half* PwsH = (__half*)Ss;
  float* qs = u0;
  float* ksp = u0 + 520;
  __half* vasH = (__half*)u0;
  int t = threadIdx.x;
  const short* Qbase = qkva + ((size_t)(n * 256 + g * 32) * 65) * 128 + w;

  // phase 1: stage q (ch 0..7) and k (ch 8..15) from qkva
  for (int l = t; l < 1040; l += 256) {
    int cc = l / 65, a = l - cc * 65;
    float v = b2f(Qbase[(size_t)l * 128]);
    if (cc < 8) qs[cc * 65 + a] = v;
    else ksp[(cc - 8) * 68 + a] = v;
  }
  __syncthreads();

  // phase 2: sim 65x65 (BN-combined qk+qr+kr), j-quad vectorized
  {
    float sqk = sg[g] * RSBN, sqr = sg[8 + g] * RSBN, skr = sg[16 + g] * RSBN;
    float badd = sb[g] + sb[8 + g] + sb[16 + g];
    for (int u = t; u < 65 * 17; u += 256) {
      int i = u / 17, jq = u - i * 17;
      float qv[8];
      #pragma unroll
      for (int c = 0; c < 8; ++c) qv[c] = qs[c * 65 + i];
      if (jq < 16) {
        int j0 = jq * 4;
        int lofs = i * 68 + j0;
        float qk0 = 0, qk1 = 0, qk2 = 0, qk3 = 0;
        float qr0 = 0, qr1 = 0, qr2 = 0, qr3 = 0;
        float kr0 = 0, kr1 = 0, kr2 = 0, kr3 = 0;
        #pragma unroll
        for (int c = 0; c < 8; ++c) {
          float4 kv = *(const float4*)&ksp[c * 68 + j0];
          float4 ra = *(const float4*)&relAp[c * 4420 + lofs];
          float4 rt = *(const float4*)&relATp[c * 4420 + lofs];
          float q = qv[c];
          qk0 += q * kv.x; qk1 += q * kv.y; qk2 += q * kv.z; qk3 += q * kv.w;
          qr0 += q * ra.x; qr1 += q * ra.y; qr2 += q * ra.z; qr3 += q * ra.w;
          kr0 += kv.x * rt.x; kr1 += kv.y * rt.y; kr2 += kv.z * rt.z; kr3 += kv.w * rt.w;
        }
        float4 res;
        res.x = sqk * qk0 + sqr * qr0 + skr * kr0 + badd;
        res.y = sqk * qk1 + sqr * qr1 + skr * kr1 + badd;
        res.z = sqk * qk2 + sqr * qr2 + skr * kr2 + badd;
        res.w = sqk * qk3 + sqr * qr3 + skr * kr3 + badd;
        *(float4*)&Ss[lofs] = res;
      } else {
        float qk = 0, qr = 0, kr = 0;
        int lofs = i * 68 + 64;
        #pragma unroll
        for (int c = 0; c < 8; ++c) {
          float kv = ksp[c * 68 + 64];
          qk += qv[c] * kv;
          qr += qv[c] * relAp[c * 4420 + lofs];
          kr += kv * relATp[c * 4420 + lofs];
        }
        Ss[lofs] = sqk * qk + sqr * qr + skr * kr + badd;
      }
    }
  }
  __syncthreads();

  // phase 3: v stage (overlays u0) + register-T softmax fold (Pw overwrites Ss after sync)
  for (int l = t; l < 16 * 66; l += 256) {
    int c = l / 66, a = l - c * 66;
    float v = (a < 65) ? b2f(Qbase[(size_t)((16 + c) * 65 + a) * 128]) : 0.f;
    vasH[l] = __float2half(v);
  }
  {
    const int i = t >> 1, h = t & 1;
    int ia, ib; float fi;
    rz_taps(i, 65.0f / 128.0f, 65, ia, ib, fi);
    const float* r0 = Ss + ia * 68 + h * 32;
    const float* r1 = Ss + ib * 68 + h * 32;
    const float wi0 = 1.0f - fi;
    float T[33];
    #pragma unroll
    for (int k = 0; k < 33; ++k) T[k] = wi0 * r0[k] + fi * r1[k];
    float mx = T[0];
    #pragma unroll
    for (int k = 1; k < 33; ++k) mx = fmaxf(mx, T[k]);
    mx = fmaxf(mx, __shfl_xor(mx, 1));
    float p[33];
    #pragma unroll
    for (int k = 0; k < 33; ++k) p[k] = 0.f;
    float sum = 0.f;
    if (h == 0) {
      #pragma unroll
      for (int j = 0; j < 64; ++j) {
        JTAP(j, ja, jb, fj);
        float v = (1.0f - fj) * T[ja] + fj * T[jb];
        float e = __expf(v - mx);
        sum += e;
        p[ja] += e * (1.0f - fj);
        p[jb] += e * fj;
      }
    } else {
      #pragma unroll
      for (int j = 64; j < 128; ++j) {
        JTAP(j, ja, jb, fj);
        float v = (1.0f - fj) * T[ja - 32] + fj * T[jb - 32];
        float e = __expf(v - mx);
        sum += e;
        p[ja - 32] += e * (1.0f - fj);
        p[jb - 32] += e * fj;
      }
    }
    sum += __shfl_xor(sum, 1);
    float other = __shfl_xor(h ? p[0] : p[32], 1);
    __syncthreads();   // all Ss reads complete before Pw overwrites the same LDS
    __half* prow = &PwsH[i * 66];
    if (h == 0) {
      p[32] += other;
      #pragma unroll
      for (int k = 0; k < 33; ++k) prow[k] = __float2half(p[k]);
      Pinvs[i] = 1.0f / sum;
    } else {
      p[0] += other;
      #pragma unroll
      for (int k = 0; k < 33; ++k) prow[32 + k] = __float2half(p[k]);
      prow[65] = __float2half(0.f);
    }
  }
  __syncthreads();

  // phase 4: dot2 contraction; writes yT[n][c2][w*128+i] -> lane=i coalesced
  {
    const int i = t & 127;
    const int cg = t >> 7;
    const float inv = Pinvs[i];
    hf2 pw[33];
    const hf2* prow2 = (const hf2*)&PwsH[i * 66];
    #pragma unroll
    for (int ap = 0; ap < 33; ++ap) pw[ap] = prow2[ap];
    #pragma unroll
    for (int l = 0; l < 8; ++l) {
      const int c = cg * 8 + l;
      const hf2* vr = (const hf2*)&vasH[c * 66];
      const hf2* vp = (const hf2*)veA + (size_t)(c * 33) * 128 + i;
      float sv0 = 0.f, sv1 = 0.f, se0 = 0.f, se1 = 0.f;
      #pragma unroll
      for (int ap = 0; ap < 32; ap += 2) {
        sv0 = __builtin_amdgcn_fdot2(vr[ap], pw[ap], sv0, false);
        sv1 = __builtin_amdgcn_fdot2(vr[ap + 1], pw[ap + 1], sv1, false);
        se0 = __builtin_amdgcn_fdot2(vp[(size_t)ap * 128], pw[ap], se0, false);
        se1 = __builtin_amdgcn_fdot2(vp[(size_t)(ap + 1) * 128], pw[ap + 1], se1, false);
      }
      sv0 = __builtin_amdgcn_fdot2(vr[32], pw[32], sv0, false);
      se0 = __builtin_amdgcn_fdot2(vp[(size_t)32 * 128], pw[32], se0, false);
      float sv = sv0 + sv1, se = se0 + se1;
      int c2 = g * 16 + c;
      int o0 = 2 * c2;
      float val = og[o0] * RSBN * (sv * inv) + ob[o0]
                + og[o0 + 1] * RSBN * (se * inv) + ob[o0 + 1];
      yT[((size_t)(n * 128 + c2)) * 16384 + w * 128 + i] = val;
    }
  }
}

// ---------- XS: stage yT plane (fp32 LDS), emit xnb (shift+IN, bf16) + yStd (fp32) ----------
// grid 316: blocks 0..255 = (n, output cx); 256..315 = (n, ch 10..39) yStd-only.
__global__ __launch_bounds__(256) void k_xs(const float* __restrict__ yT,
                                            const float* __restrict__ inw,
                                            const float* __restrict__ inb,
                                            short* __restrict__ xnb,
                                            float* __restrict__ yStd) {
  int gid = blockIdx.x;
  int n, cs, cx = -1;
  bool wStd;
  if (gid < 256) {
    n = gid >> 7; cx = gid & 127;
    cs = (cx < 40) ? (cx % 10) : cx;
    wStd = (cx < 10) || (cx >= 40);
  } else {
    int u = gid - 256;
    n = u / 30; cs = 10 + (u % 30);
    wStd = true;
  }
  int dh = 0, dw = 0;
  if (cx >= 0) {
    if (cx < 10)       dw = -2;
    else if (cx < 20)  dw = 2;
    else if (cx < 30)  dh = -2;
    else if (cx < 40)  dh = 2;
  }
  __shared__ float Sb[128 * 130];   // [w][i], stride 130 floats
  __shared__ float sm[8];
  const float* src = yT + ((size_t)(n * 128 + cs)) * 16384;
  int t = threadIdx.x;
  #pragma unroll
  for (int l = 0; l < 16; ++l) {
    int q = t + l * 256;
    float4 v = *(const float4*)&src[q * 4];    // 4 consecutive i, fixed w
    int w = q >> 5, i0 = (q * 4) & 127;
    float* d = &Sb[w * 130 + i0];
    *(float2*)d = make_float2(v.x, v.y);
    *(float2*)(d + 2) = make_float2(v.z, v.w);
  }
  __syncthreads();
  if (wStd) {   // exact fp32 pass-through, standard (i,w) order
    float* dst = yStd + ((size_t)(n * 128 + cs)) * 16384;
    for (int l = 0; l < 64; ++l) {
      int idx = t + l * 256;
      int h = idx >> 7, w = idx & 127;
      dst[idx] = Sb[w * 130 + h];
    }
  }
  if (cx >= 0) {
    float s = 0.f, q2 = 0.f;
    for (int l = 0; l < 64; ++l) {
      int idx = t + l * 256;
      int h = idx >> 7, w = idx & 127;
      int hs = h + dh, ws = w + dw;
      float v = (hs >= 0 && hs < 128 && ws >= 0 && ws < 128) ? Sb[ws * 130 + hs] : 0.f;
      s += v; q2 += v * v;
    }
    #pragma unroll
    for (int o = 32; o; o >>= 1) { s += __shfl_down(s, o); q2 += __shfl_down(q2, o); }
    if ((t & 63) == 0) { sm[(t >> 6) * 2] = s; sm[(t >> 6) * 2 + 1] = q2; }
    __syncthreads();
    float S_ = sm[0] + sm[2] + sm[4] + sm[6];
    float Q_ = sm[1] + sm[3] + sm[5] + sm[7];
    float mean = S_ * (1.0f / 16384.0f);
    float var = Q_ * (1.0f / 16384.0f) - mean * mean;
    float scale = inw[cx] * rsqrtf(var + 1e-5f);
    float shift = inb[cx] - mean * scale;
    short* dst = xnb + ((size_t)(n * 128 + cx)) * 16384;
    for (int l = 0; l < 64; ++l) {
      int idx = t + l * 256;
      int h = idx >> 7, w = idx & 127;
      int hs = h + dh, ws = w + dw;
      float v = (hs >= 0 && hs < 128 && ws >= 0 && ws < 128) ? Sb[ws * 130 + hs] : 0.f;
      dst[idx] = f2b(v * scale + shift);
    }
  }
}

// ---------- MFMA GEMM 2: h1 = gelu(W1 . xn) ----------
__global__ __launch_bounds__(256) void k_mlp1_mfma(
    const short* __restrict__ xnb, const short* __restrict__ w1b,
    short* __restrict__ h1) {
  const int ob = blockIdx.x * 128;
  const int pb = blockIdx.y * 128;
  const int n = blockIdx.z;
  __shared__ short Asm[128 * 40];
  __shared__ short Bsm[128 * 40];
  const int t = threadIdx.x;
  const int lane = t & 63, wv = t >> 6;
  const int wm = wv >> 1, wn = wv & 1;
  const int lr = lane & 15, lk = (lane >> 4) * 8;
  f32x4 acc[4][4];
  #pragma unroll
  for (int i = 0; i < 4; ++i)
    #pragma unroll
    for (int j = 0; j < 4; ++j)
      #pragma unroll
      for (int q = 0; q < 4; ++q) acc[i][j][q] = 0.f;
  const short* X = xnb + (size_t)n * 128 * 16384;
  for (int k0 = 0; k0 < 128; k0 += 32) {
    #pragma unroll
    for (int i2 = 0; i2 < 2; ++i2) {
      int u = t + 256 * i2;
      int row = u >> 2, kq = (u & 3) * 8;
      *(bf16x8*)&Asm[row * 40 + kq] = *(const bf16x8*)&w1b[(ob + row) * 128 + k0 + kq];
    }
    #pragma unroll
    for (int i2 = 0; i2 < 2; ++i2) {
      int u = t + 256 * i2;
      int k = u >> 4, p8 = (u & 15) * 8;
      bf16x8 hv = *(const bf16x8*)&X[(size_t)(k0 + k) * 16384 + pb + p8];
      #pragma unroll
      for (int j = 0; j < 8; ++j) Bsm[(p8 + j) * 40 + k] = hv[j];
    }
    __syncthreads();
    bf16x8 af[4], bfr[4];
    #pragma unroll
    for (int mf = 0; mf < 4; ++mf) af[mf] = *(bf16x8*)&Asm[(wm * 64 + mf * 16 + lr) * 40 + lk];
    #pragma unroll
    for (int nf = 0; nf < 4; ++nf) bfr[nf] = *(bf16x8*)&Bsm[(wn * 64 + nf * 16 + lr) * 40 + lk];
    #pragma unroll
    for (int mf = 0; mf < 4; ++mf)
      #pragma unroll
      for (int nf = 0; nf < 4; ++nf)
        acc[mf][nf] = MFMA16(af[mf], bfr[nf], acc[mf][nf]);
    __syncthreads();
  }
  #pragma unroll
  for (int mf = 0; mf < 4; ++mf)
    #pragma unroll
    for (int r = 0; r < 4; ++r) {
      int o = ob + wm * 64 + mf * 16 + (lane >> 4) * 4 + r;
      #pragma unroll
      for (int nf = 0; nf < 4; ++nf) {
        int p = pb + wn * 64 + nf * 16 + lr;
        h1[((size_t)(n * 512 + o)) * 16384 + p] = f2b(gelu_exact(acc[mf][nf][r]));
      }
    }
}

// ---------- MFMA GEMM 3: out = W2 . h1 + identity(yStd) ----------
__global__ __launch_bounds__(256) void k_mlp2_mfma(
    const short* __restrict__ h1, const short* __restrict__ w2b,
    const float* __restrict__ y, float* __restrict__ out) {
  const int pb = blockIdx.x * 128;
  const int ob = blockIdx.y * 128;
  const int n = blockIdx.z;
  __shared__ short Asm[128 * 40];
  __shared__ short Bsm[128 * 40];
  const int t = threadIdx.x;
  const int lane = t & 63, wv = t >> 6;
  const int wm = wv >> 1, wn = wv & 1;
  const int lr = lane & 15, lk = (lane >> 4) * 8;
  f32x4 acc[4][4];
  #pragma unroll
  for (int i = 0; i < 4; ++i)
    #pragma unroll
    for (int j = 0; j < 4; ++j)
      #pragma unroll
      for (int q = 0; q < 4; ++q) acc[i][j][q] = 0.f;
  const short* H = h1 + (size_t)n * 512 * 16384;
  for (int k0 = 0; k0 < 512; k0 += 32) {
    #pragma unroll
    for (int i2 = 0; i2 < 2; ++i2) {
      int u = t + 256 * i2;
      int row = u >> 2, kq = (u & 3) * 8;
      *(bf16x8*)&Asm[row * 40 + kq] = *(const bf16x8*)&w2b[(ob + row) * 512 + k0 + kq];
    }
    #pragma unroll
    for (int i2 = 0; i2 < 2; ++i2) {
      int u = t + 256 * i2;
      int k = u >> 4, p8 = (u & 15) * 8;
      bf16x8 hv = *(const bf16x8*)&H[(size_t)(k0 + k) * 16384 + pb + p8];
      #pragma unroll
      for (int j = 0; j < 8; ++j) Bsm[(p8 + j) * 40 + k] = hv[j];
    }
    __syncthreads();
    bf16x8 af[4], bfr[4];
    #pragma unroll
    for (int mf = 0; mf < 4; ++mf) af[mf] = *(bf16x8*)&Asm[(wm * 64 + mf * 16 + lr) * 40 + lk];
    #pragma unroll
    for (int nf = 0; nf < 4; ++nf) bfr[nf] = *(bf16x8*)&Bsm[(wn * 64 + nf * 16 + lr) * 40 + lk];
    #pragma unroll
    for (int mf = 0; mf < 4; ++mf)
      #pragma unroll
      for (int nf = 0; nf < 4; ++nf)
        acc[mf][nf] = MFMA16(af[mf], bfr[nf], acc[mf][nf]);
    __syncthreads();
  }
  #pragma unroll
  for (int mf = 0; mf < 4; ++mf)
    #pragma unroll
    for (int r = 0; r < 4; ++r) {
      int o = ob + wm * 64 + mf * 16 + (lane >> 4) * 4 + r;
      #pragma unroll
      for (int nf = 0; nf < 4; ++nf) {
        int p = pb + wn * 64 + nf * 16 + lr;
        size_t base = ((size_t)(n * 128 + o)) * 16384 + p;
        out[base] = acc[mf][nf][r] + y[base];
      }
    }
}

extern "C" void kernel_launch(void* const* d_in, const int* in_sizes, int n_in,
                              void* d_out, int out_size, void* d_ws, size_t ws_size,
                              hipStream_t stream) {
  const float* x        = (const float*)d_in[0];
  const float* w_qkv    = (const float*)d_in[1];
  const float* bn_qkv_g = (const float*)d_in[2];
  const float* bn_qkv_b = (const float*)d_in[3];
  const float* bn_sim_g = (const float*)d_in[4];
  const float* bn_sim_b = (const float*)d_in[5];
  const float* bn_out_g = (const float*)d_in[6];
  const float* bn_out_b = (const float*)d_in[7];
  const float* in_w     = (const float*)d_in[8];
  const float* in_b     = (const float*)d_in[9];
  const float* mlp_w1   = (const float*)d_in[10];
  const float* mlp_w2   = (const float*)d_in[11];
  const float* base_rel = (const float*)d_in[12];
  float* Wp = (float*)d_ws;

  float* relAp  = Wp + 0;            // 35,456
  float* relATp = Wp + 35456;        // 35,456
  __half* veA   = (__half*)(Wp + 70912);     // 135,168 halves (67,584 f)
  float* yT     = Wp + 138496;       // 4,194,304
  float* yStd   = Wp + 4332800;      // 4,194,304
  short* wqb    = (short*)(Wp + 8527104);    // 32,768 shorts
  short* w1b    = (short*)(Wp + 8543488);    // 65,536 shorts
  short* w2b    = (short*)(Wp + 8576256);    // 65,536 shorts
  short* xnb    = (short*)(Wp + 8609024);    // 4,194,304 shorts
  short* xab    = (short*)(Wp + 10706176);   // 2,129,920 shorts (dead after qkv)
  short* qkva   = (short*)(Wp + 11771136);   // 4,259,840 shorts (dead after attn)
  short* h1b    = (short*)(Wp + 10706176);   // 16,777,216 shorts (overlays xab+qkva)
  // peak: 19,094,784 floats = 76.4 MB

  k_prep<<<dim3(1049), dim3(256), 0, stream>>>(base_rel, w_qkv, mlp_w1, mlp_w2,
                                               wqb, w1b, w2b, relAp, relATp, veA);
  k_xa<<<dim3(8320), dim3(256), 0, stream>>>(x, xab);
  k_qkv_mfma<<<dim3(2, 65, 2), dim3(256), 0, stream>>>(xab, wqb, bn_qkv_g, bn_qkv_b, qkva);
  k_attn<<<dim3(2048), dim3(256), 0, stream>>>(qkva, relAp, relATp, veA,
                                               bn_sim_g, bn_sim_b, bn_out_g, bn_out_b, yT);
  k_xs<<<dim3(316), dim3(256), 0, stream>>>(yT, in_w, in_b, xnb, yStd);
  k_mlp1_mfma<<<dim3(4, 128, 2), dim3(256), 0, stream>>>(xnb, w1b, h1b);
  k_mlp2_mfma<<<dim3(128, 1, 2), dim3(256), 0, stream>>>(h1b, w2b, yStd, (float*)d_out);
}